// Round 1
// baseline (302.664 us; speedup 1.0000x reference)
//
#include <hip/hip_runtime.h>

#define NB1   123
#define NCSd  96
#define SW    538
#define BT    16
#define TPB   128
#define TOLf  1e-6f

__global__ void k_transpose(const float* __restrict__ Kre,
                            const float* __restrict__ Kim,
                            float2* __restrict__ kt) {
    int idx = blockIdx.x * blockDim.x + threadIdx.x;   // 0..16383
    if (idx >= TPB * TPB) return;
    int k = idx >> 7, j = idx & (TPB - 1);
    float2 v = make_float2(0.f, 0.f);
    if (k < NB1 && j < NB1) { v.x = Kre[j * NB1 + k]; v.y = Kim[j * NB1 + k]; }
    kt[idx] = v;
}

template<bool USE_KT>
__global__ __launch_bounds__(TPB) void k_main(
    const float* __restrict__ action,
    const float* __restrict__ state,
    const float* __restrict__ Kre,
    const float* __restrict__ Kim,
    const float* __restrict__ Lre,
    const float* __restrict__ Lim,
    const float2* __restrict__ kt,
    float* __restrict__ out)
{
    __shared__ float ev[BT][TPB];                        // ev_bus per element
    __shared__ float costs_s[BT];
    __shared__ float usat_s[BT];
    __shared__ __align__(16) float2 cmat[TPB][BT + 2];   // c[k][e], 18 f2/row = 144B (16B aligned rows)
    __shared__ float vls[TPB][BT + 1];
    __shared__ float red[2];

    const int tid = threadIdx.x;
    const int e0  = blockIdx.x * BT;

    for (int x = tid; x < BT * TPB; x += TPB) ((float*)ev)[x] = 0.f;
    if (tid < BT) { costs_s[tid] = 0.f; usat_s[tid] = 0.f; }
    __syncthreads();

    // ---- Phase A: EV elementwise + scatter onto buses ----
    for (int task = tid; task < BT * NCSd; task += TPB) {
        int e = task / NCSd;
        int i = task - e * NCSd;
        long b = (long)(e0 + e);
        const float* srow = state + b * SW;
        float cap   = srow[250 + 3 * i];
        float tleft = srow[251 + 3 * i];
        int   bus   = (int)srow[252 + 3 * i];
        float a     = action[b * NCSd + i];
        float conn  = cap > 0.f ? 1.f : 0.f;
        float max_ch  = fminf(22.0f,  conn * (70.0f - cap) * 4.0f);   // /DT, DT=0.25 exact
        float max_dis = fmaxf(-22.0f, conn * (15.0f - cap) * 4.0f);
        float power = 22.17f * a;                                     // MAX_CS = -MIN_CS
        power = fmaxf(fminf(power, max_ch), max_dis);
        float prices = srow[3];
        atomicAdd(&costs_s[e], prices * power * 0.25f);
        float new_cap = ceilf((cap + power * 0.25f) * 100.0f) / 100.0f;
        if (tleft == 1.0f) {
            float d = new_cap - 70.0f;
            atomicAdd(&usat_s[e], -10.0f * d * d);
        }
        atomicAdd(&ev[e][bus], power);
    }
    __syncthreads();

    // ---- Phase B: power-flow fixed point, thread = bus j, BT elems in regs ----
    const int j = tid;
    const bool jok = j < NB1;
    float Wre = jok ? Lre[j] : 1.0f;
    float Wim = jok ? Lim[j] : 0.0f;

    float Sre[BT], Sim[BT], vr[BT], vi[BT];
    #pragma unroll
    for (int e = 0; e < BT; ++e) {
        long b = (long)(e0 + e);
        float ap = jok ? state[b * SW + 4 + j]   : 0.f;
        float rp = jok ? state[b * SW + 127 + j] : 0.f;
        Sre[e] = (ap + ev[e][j]) / 1000.0f;
        Sim[e] = rp / 1000.0f;
        vr[e] = 1.f; vi[e] = 0.f;
    }

    for (int it = 0; it < 100; ++it) {
        // c = conj(S/v) = conj(S)*v / |v|^2
        #pragma unroll
        for (int e = 0; e < BT; ++e) {
            float d   = vr[e] * vr[e] + vi[e] * vi[e];
            float inv = 1.0f / d;
            float cr  = (Sre[e] * vr[e] + Sim[e] * vi[e]) * inv;
            float ci  = (Sre[e] * vi[e] - Sim[e] * vr[e]) * inv;
            cmat[j][e] = make_float2(cr, ci);
        }
        __syncthreads();

        float ar[BT], ai[BT];
        #pragma unroll
        for (int e = 0; e < BT; ++e) { ar[e] = Wre; ai[e] = Wim; }

        for (int k = 0; k < NB1; ++k) {
            float2 kc;
            if (USE_KT) {
                kc = kt[k * TPB + j];                       // coalesced, L2-resident
            } else {
                kc.x = jok ? Kre[j * NB1 + k] : 0.f;
                kc.y = jok ? Kim[j * NB1 + k] : 0.f;
            }
            const float4* crow = (const float4*)(&cmat[k][0]);   // broadcast reads
            #pragma unroll
            for (int eh = 0; eh < BT / 2; ++eh) {
                float4 c2 = crow[eh];
                ar[2*eh]   = fmaf(kc.x, c2.x, fmaf(-kc.y, c2.y, ar[2*eh]));
                ai[2*eh]   = fmaf(kc.x, c2.y, fmaf( kc.y, c2.x, ai[2*eh]));
                ar[2*eh+1] = fmaf(kc.x, c2.z, fmaf(-kc.y, c2.w, ar[2*eh+1]));
                ai[2*eh+1] = fmaf(kc.x, c2.w, fmaf( kc.y, c2.z, ai[2*eh+1]));
            }
        }

        float md = 0.f;
        #pragma unroll
        for (int e = 0; e < BT; ++e) {
            float vmn = sqrtf(ar[e]*ar[e] + ai[e]*ai[e]);
            float vmo = sqrtf(vr[e]*vr[e] + vi[e]*vi[e]);
            md = fmaxf(md, fabsf(vmn - vmo));
            vr[e] = ar[e]; vi[e] = ai[e];
        }
        #pragma unroll
        for (int off = 32; off > 0; off >>= 1)
            md = fmaxf(md, __shfl_xor(md, off));
        if ((tid & 63) == 0) red[tid >> 6] = md;
        __syncthreads();
        if (fmaxf(red[0], red[1]) < TOLf) break;
    }

    // ---- Epilogue: voltage loss + combine ----
    #pragma unroll
    for (int e = 0; e < BT; ++e) {
        float vm = sqrtf(vr[e]*vr[e] + vi[e]*vi[e]);
        float vl = fminf(0.f, 0.05f - fabsf(1.0f - vm));
        vls[j][e] = jok ? vl : 0.f;
    }
    __syncthreads();
    if (tid < BT) {
        float s = 0.f;
        for (int k = 0; k < NB1; ++k) s += vls[k][tid];
        out[e0 + tid] = 1000.0f * s + costs_s[tid] + usat_s[tid];
    }
}

extern "C" void kernel_launch(void* const* d_in, const int* in_sizes, int n_in,
                              void* d_out, int out_size, void* d_ws, size_t ws_size,
                              hipStream_t stream) {
    const float* action = (const float*)d_in[0];
    const float* state  = (const float*)d_in[1];
    const float* Kre    = (const float*)d_in[2];
    const float* Kim    = (const float*)d_in[3];
    const float* Lre    = (const float*)d_in[4];
    const float* Lim    = (const float*)d_in[5];
    float* out = (float*)d_out;

    int B = out_size;                       // 32768
    int nblocks = (B + BT - 1) / BT;        // 2048

    size_t ktBytes = (size_t)TPB * TPB * sizeof(float2);
    if (ws_size >= ktBytes) {
        float2* kt = (float2*)d_ws;
        hipLaunchKernelGGL(k_transpose, dim3((TPB * TPB) / 256), dim3(256), 0, stream,
                           Kre, Kim, kt);
        hipLaunchKernelGGL(k_main<true>, dim3(nblocks), dim3(TPB), 0, stream,
                           action, state, Kre, Kim, Lre, Lim, kt, out);
    } else {
        hipLaunchKernelGGL(k_main<false>, dim3(nblocks), dim3(TPB), 0, stream,
                           action, state, Kre, Kim, Lre, Lim, (const float2*)nullptr, out);
    }
}